// Round 5
// baseline (1683.651 us; speedup 1.0000x reference)
//
#include <hip/hip_runtime.h>
#include <stdint.h>

typedef short short8 __attribute__((ext_vector_type(8)));
typedef float floatx4 __attribute__((ext_vector_type(4)));
typedef float floatx16 __attribute__((ext_vector_type(16)));

#define NPTS 16384
#define THREADS 512
#define PA 3   // A-fragment (LDS) prefetch depth
#define PB 6   // B-fragment (global/L2) prefetch depth

__device__ inline unsigned short f2bf(float f) {
  union { float f; unsigned u; } v; v.f = f;
  unsigned u = v.u;
  unsigned r = (u + 0x7fffu + ((u >> 16) & 1u)) >> 16;
  return (unsigned short)r;
}
__device__ inline float bf2f(unsigned short h) {
  union { unsigned u; float f; } v; v.u = ((unsigned)h) << 16;
  return v.f;
}

// Residual GEMM: act = relu(act@W.T + b) + act, 64x512x512, 8 waves (2mt x 2nt).
// Entry: act ready (barrier done), bq holds bptr slabs [0..PB-2].
// Exit: bq holds nbptr slabs [0..PB-2] (prefetched before the epilogue barrier).
__device__ __forceinline__ void gemm_block(
    const short8* __restrict__ bptr, const short8* __restrict__ nbptr,
    const float* __restrict__ bias,
    short8 (&bq0)[PB], short8 (&bq1)[PB],
    const char* actB, int aBase, int bidx0, int bidx1,
    int wid, int lane, unsigned short (*act)[520])
{
  floatx16 acc00{}, acc01{}, acc10{}, acc11{};
  short8 aq0[PA], aq1[PA];
  #pragma unroll
  for (int i = 0; i < PA - 1; ++i) {
    aq0[i] = *(const short8*)(actB + aBase + i * 32);
    aq1[i] = *(const short8*)(actB + aBase + 33280 + i * 32);
  }
  #pragma unroll
  for (int kt = 0; kt < 32; ++kt) {
    int la = kt + PA - 1;
    if (la < 32) {
      aq0[la % PA] = *(const short8*)(actB + aBase + la * 32);
      aq1[la % PA] = *(const short8*)(actB + aBase + 33280 + la * 32);
    }
    int lb = kt + PB - 1;
    if (lb < 32) {
      bq0[lb % PB] = bptr[lb * 1024 + bidx0];
      bq1[lb % PB] = bptr[lb * 1024 + bidx1];
    }
    acc00 = __builtin_amdgcn_mfma_f32_32x32x16_bf16(aq0[kt % PA], bq0[kt % PB], acc00, 0, 0, 0);
    acc01 = __builtin_amdgcn_mfma_f32_32x32x16_bf16(aq0[kt % PA], bq1[kt % PB], acc01, 0, 0, 0);
    acc10 = __builtin_amdgcn_mfma_f32_32x32x16_bf16(aq1[kt % PA], bq0[kt % PB], acc10, 0, 0, 0);
    acc11 = __builtin_amdgcn_mfma_f32_32x32x16_bf16(aq1[kt % PA], bq1[kt % PB], acc11, 0, 0, 0);
  }
  // prefetch next GEMM's first slabs (in flight across epilogue + later phases)
  #pragma unroll
  for (int i = 0; i < PB - 1; ++i) {
    bq0[i] = nbptr[i * 1024 + bidx0];
    bq1[i] = nbptr[i * 1024 + bidx1];
  }
  __syncthreads();
  int col = lane & 31;
  int ncol0 = (wid * 2 + 0) * 32 + col;
  int ncol1 = (wid * 2 + 1) * 32 + col;
  float bs0 = bias[ncol0], bs1 = bias[ncol1];
  int rb = 4 * (lane >> 5);
  #pragma unroll
  for (int reg = 0; reg < 16; ++reg) {
    int row = (reg & 3) + 8 * (reg >> 2) + rb;
    float v = fmaxf(acc00[reg] + bs0, 0.f) + bf2f(act[row][ncol0]);
    act[row][ncol0] = f2bf(v);
    v = fmaxf(acc01[reg] + bs1, 0.f) + bf2f(act[row][ncol1]);
    act[row][ncol1] = f2bf(v);
    v = fmaxf(acc10[reg] + bs0, 0.f) + bf2f(act[row + 32][ncol0]);
    act[row + 32][ncol0] = f2bf(v);
    v = fmaxf(acc11[reg] + bs1, 0.f) + bf2f(act[row + 32][ncol1]);
    act[row + 32][ncol1] = f2bf(v);
  }
  __syncthreads();
}

// Entire 2-block NODE integration for 64 points per WG (pointwise ODE: no
// inter-WG dependency). 32 dyn evals in one launch; RK4 state lives in LDS.
__global__ __launch_bounds__(THREADS, 2) void node_kernel(
    const float* __restrict__ x, float* __restrict__ outp,
    const unsigned short* __restrict__ wfrag,   // [4][512*512] f1w2,f1w3,f2w2,f2w3
    const unsigned short* __restrict__ w1frag,  // [2][8192]  K-padded W1 B-frags
    const unsigned short* __restrict__ w4frag,  // [2][16384] N-padded W4^T B-frags
    const float* __restrict__ sfall,            // [2][4*512]
    const float* __restrict__ b1a, const float* __restrict__ b2a,
    const float* __restrict__ b3a, const float* __restrict__ b4a,
    const float* __restrict__ b1b, const float* __restrict__ b2b,
    const float* __restrict__ b3b, const float* __restrict__ b4b)
{
  __shared__ unsigned short act[64][520];   // pitch 520 u16: conflict-benign b128
  __shared__ float pcur[64][4];
  __shared__ float pev[64][4];
  __shared__ float kst[4][64][4];
  __shared__ float pred[8][64][4];

  const int tid = threadIdx.x;
  const int lane = tid & 63;
  const int wid = tid >> 6;
  const int wg = blockIdx.x;
  const int m0 = wg * 64;
  const int batch = wg >> 6;

  if (tid < 256) {
    int m = tid >> 2, c = tid & 3;
    pcur[m][c] = (c < 3) ? x[m0 * 3 + m * 3 + c] : 0.f;
  }
  __syncthreads();

  const int aBase = (lane & 31) * 1040 + (lane >> 5) * 16;
  const char* actB = (const char*)&act[0][0];
  const int bidx0 = (wid * 2 + 0) * 64 + lane;
  const int bidx1 = (wid * 2 + 1) * 64 + lane;

  const float dt = 0.05f, hdt = 0.025f, dt6 = dt / 6.0f;

  short8 bq0[PB], bq1[PB];
  {  // initial preload: f1 GEMM1 (w2) slabs
    const short8* bp = (const short8*)wfrag;
    #pragma unroll
    for (int i = 0; i < PB - 1; ++i) {
      bq0[i] = bp[i * 1024 + bidx0];
      bq1[i] = bp[i * 1024 + bidx1];
    }
  }

  for (int f = 0; f < 2; ++f) {
    const short8* w2p = (const short8*)(wfrag + (2 * f + 0) * 262144);
    const short8* w3p = (const short8*)(wfrag + (2 * f + 1) * 262144);
    const short8* w1p = (const short8*)(w1frag + f * 8192);
    const short8* w4p = (const short8*)(w4frag + f * 16384);
    const float* sff = sfall + f * 2048 + batch * 512;
    const float* b1 = f ? b1b : b1a;
    const float* b2 = f ? b2b : b2a;
    const float* b3 = f ? b3b : b3a;
    const float* b4 = f ? b4b : b4a;

    for (int step = 0; step < 4; ++step) {
      for (int stage = 0; stage < 4; ++stage) {
        // ---- p_eval ----
        if (tid < 256) {
          int m = tid >> 2, c = tid & 3;
          if (stage == 0) {
            pev[m][c] = pcur[m][c];
          } else {
            float cf = (stage == 3) ? dt : hdt;
            pev[m][c] = fmaf(cf, kst[stage - 1][m][c], pcur[m][c]);
          }
        }
        __syncthreads();

        // ---- phase 1 (MFMA, K=3 zero-padded to 16): act = relu(pe@W1.T+b1)*sf ----
        {
          floatx4 p0 = *(const floatx4*)&pev[lane & 31][0];
          floatx4 p1 = *(const floatx4*)&pev[(lane & 31) + 32][0];
          short8 A0 = (short8){0, 0, 0, 0, 0, 0, 0, 0};
          short8 A1 = A0;
          if ((lane >> 5) == 0) {
            A0[0] = (short)f2bf(p0[0]); A0[1] = (short)f2bf(p0[1]); A0[2] = (short)f2bf(p0[2]);
            A1[0] = (short)f2bf(p1[0]); A1[1] = (short)f2bf(p1[1]); A1[2] = (short)f2bf(p1[2]);
          }
          short8 B0 = w1p[bidx0], B1 = w1p[bidx1];
          floatx16 c00{}, c01{}, c10{}, c11{};
          c00 = __builtin_amdgcn_mfma_f32_32x32x16_bf16(A0, B0, c00, 0, 0, 0);
          c01 = __builtin_amdgcn_mfma_f32_32x32x16_bf16(A0, B1, c01, 0, 0, 0);
          c10 = __builtin_amdgcn_mfma_f32_32x32x16_bf16(A1, B0, c10, 0, 0, 0);
          c11 = __builtin_amdgcn_mfma_f32_32x32x16_bf16(A1, B1, c11, 0, 0, 0);
          int col = lane & 31;
          int ncol0 = (wid * 2 + 0) * 32 + col;
          int ncol1 = (wid * 2 + 1) * 32 + col;
          float bb0 = b1[ncol0], bb1 = b1[ncol1];
          float s0 = sff[ncol0], s1 = sff[ncol1];
          int rb = 4 * (lane >> 5);
          #pragma unroll
          for (int reg = 0; reg < 16; ++reg) {
            int row = (reg & 3) + 8 * (reg >> 2) + rb;
            act[row][ncol0]      = f2bf(fmaxf(c00[reg] + bb0, 0.f) * s0);
            act[row][ncol1]      = f2bf(fmaxf(c01[reg] + bb1, 0.f) * s1);
            act[row + 32][ncol0] = f2bf(fmaxf(c10[reg] + bb0, 0.f) * s0);
            act[row + 32][ncol1] = f2bf(fmaxf(c11[reg] + bb1, 0.f) * s1);
          }
        }
        __syncthreads();

        // ---- GEMM1 (next: w3), GEMM2 (next: following dyn's w2) ----
        gemm_block(w2p, w3p, b2, bq0, bq1, actB, aBase, bidx0, bidx1, wid, lane, act);
        const short8* nxt = (f == 0 && step == 3 && stage == 3)
                                ? (const short8*)(wfrag + 2 * 262144) : w2p;
        gemm_block(w3p, nxt, b3, bq0, bq1, actB, aBase, bidx0, bidx1, wid, lane, act);

        // ---- phase 4 (MFMA, N=3 zero-padded): flow = tanh(act@W4.T + b4) ----
        {
          floatx16 d0{}, d1{};
          #pragma unroll
          for (int kk = 0; kk < 4; ++kk) {
            int kt = wid * 4 + kk;
            short8 a0 = *(const short8*)(actB + aBase + kt * 32);
            short8 a1 = *(const short8*)(actB + aBase + 33280 + kt * 32);
            short8 b = w4p[kt * 64 + lane];
            d0 = __builtin_amdgcn_mfma_f32_32x32x16_bf16(a0, b, d0, 0, 0, 0);
            d1 = __builtin_amdgcn_mfma_f32_32x32x16_bf16(a1, b, d1, 0, 0, 0);
          }
          int col = lane & 31;
          int rb = 4 * (lane >> 5);
          if (col < 3) {
            #pragma unroll
            for (int reg = 0; reg < 16; ++reg) {
              int row = (reg & 3) + 8 * (reg >> 2) + rb;
              pred[wid][row][col] = d0[reg];
              pred[wid][row + 32][col] = d1[reg];
            }
          }
        }
        __syncthreads();
        // reduce 8 wave-partials + bias + tanh -> kst[stage]
        if (tid < 256) {
          int m = tid >> 2, c = tid & 3;
          if (c < 3) {
            float s = b4[c];
            #pragma unroll
            for (int w = 0; w < 8; ++w) s += pred[w][m][c];
            kst[stage][m][c] = tanhf(s);
          } else {
            kst[stage][m][3] = 0.f;
          }
        }
        __syncthreads();
      }
      // ---- RK4 update ----
      if (tid < 256) {
        int m = tid >> 2, c = tid & 3;
        pcur[m][c] += dt6 * (kst[0][m][c] + 2.f * kst[1][m][c] +
                             2.f * kst[2][m][c] + kst[3][m][c]);
      }
      __syncthreads();
    }
  }
  if (tid < 192) outp[m0 * 3 + tid] = pcur[tid / 3][tid % 3];
}

// ---- setup: shuffle W (512x512 fp32 row-major) into fragment-major bf16 ----
__global__ void setup_shuffle(const float* s0, const float* s1, const float* s2,
                              const float* s3, unsigned short* dst) {
  int idx = blockIdx.x * blockDim.x + threadIdx.x;   // 4 * 32768
  int w = idx >> 15;
  int r = idx & 32767;            // (kt*16+nt)*64 + lane
  int lane = r & 63;
  int tile = r >> 6;
  int nt = tile & 15, kt = tile >> 4;
  const float* W = (w == 0) ? s0 : (w == 1) ? s1 : (w == 2) ? s2 : s3;
  int n = nt * 32 + (lane & 31);
  int k0 = kt * 16 + (lane >> 5) * 8;
  const float* src = W + n * 512 + k0;
  unsigned short* d = dst + ((size_t)w << 18) + (size_t)r * 8;
  #pragma unroll
  for (int j = 0; j < 8; ++j) d[j] = f2bf(src[j]);
}

// W1 (512x3) K-padded and W4 (3x512) N-padded fragment buffers
__global__ void setup_small(const float* w1A, const float* w1B,
                            const float* w4A, const float* w4B,
                            unsigned short* w1frag, unsigned short* w4frag) {
  int i = blockIdx.x * blockDim.x + threadIdx.x;   // 49152
  if (i < 16384) {
    int f = i >> 13, r = i & 8191;      // (nt*64+lane)*8 + j
    int j = r & 7, lane = (r >> 3) & 63, nt = r >> 9;
    int n = nt * 32 + (lane & 31), k = (lane >> 5) * 8 + j;
    const float* w1 = f ? w1B : w1A;
    w1frag[f * 8192 + r] = (k < 3) ? f2bf(w1[n * 3 + k]) : (unsigned short)0;
  } else {
    int i2 = i - 16384;
    int f = i2 >> 14, r = i2 & 16383;   // (kt*64+lane)*8 + j
    int j = r & 7, lane = (r >> 3) & 63, kt = r >> 9;
    int n = lane & 31, k = kt * 16 + (lane >> 5) * 8 + j;
    const float* w4 = f ? w4B : w4A;
    w4frag[f * 16384 + r] = (n < 3) ? f2bf(w4[n * 512 + k]) : (unsigned short)0;
  }
}

__global__ void setup_sf(const float* code, const float* cw1, const float* cb1,
                         const float* cw2, const float* cb2, float* sfout) {
  int f = blockIdx.x >> 2, b = blockIdx.x & 3;
  const float* cw = f ? cw2 : cw1;
  const float* cb = f ? cb2 : cb1;
  int j = threadIdx.x;
  const float* c = code + b * 512;
  float s = cb[j];
  for (int k = 0; k < 512; ++k) s = fmaf(c[k], cw[j * 512 + k], s);
  sfout[f * 2048 + b * 512 + j] = tanhf(s);
}

extern "C" void kernel_launch(void* const* d_in, const int* in_sizes, int n_in,
                              void* d_out, int out_size, void* d_ws, size_t ws_size,
                              hipStream_t stream) {
  const float* code = (const float*)d_in[0];
  const float* x    = (const float*)d_in[1];
  char* ws = (char*)d_ws;
  unsigned short* wbf    = (unsigned short*)(ws);                 // 2 MB
  unsigned short* w1frag = (unsigned short*)(ws + 2097152);       // 32 KB
  unsigned short* w4frag = (unsigned short*)(ws + 2097152 + 32768); // 64 KB
  float* sf              = (float*)(ws + 2097152 + 32768 + 65536);  // 16 KB

  setup_shuffle<<<512, 256, 0, stream>>>((const float*)d_in[4], (const float*)d_in[6],
                                         (const float*)d_in[14], (const float*)d_in[16], wbf);
  setup_small<<<192, 256, 0, stream>>>((const float*)d_in[2], (const float*)d_in[12],
                                       (const float*)d_in[8], (const float*)d_in[18],
                                       w1frag, w4frag);
  setup_sf<<<8, 512, 0, stream>>>(code, (const float*)d_in[10], (const float*)d_in[11],
                                  (const float*)d_in[20], (const float*)d_in[21], sf);

  node_kernel<<<256, THREADS, 0, stream>>>(
      x, (float*)d_out, wbf, w1frag, w4frag, sf,
      (const float*)d_in[3],  (const float*)d_in[5],
      (const float*)d_in[7],  (const float*)d_in[9],
      (const float*)d_in[13], (const float*)d_in[15],
      (const float*)d_in[17], (const float*)d_in[19]);
}

// Round 6
// 1446.378 us; speedup vs baseline: 1.1640x; 1.1640x over previous
//
#include <hip/hip_runtime.h>
#include <stdint.h>

typedef short short8 __attribute__((ext_vector_type(8)));
typedef float floatx4 __attribute__((ext_vector_type(4)));
typedef float floatx16 __attribute__((ext_vector_type(16)));

#define NPTS 16384
#define THREADS 512
#define PA 3   // A-fragment (LDS) prefetch depth
#define PB 6   // B-fragment (global/L2) prefetch depth

__device__ inline unsigned short f2bf(float f) {
  union { float f; unsigned u; } v; v.f = f;
  unsigned u = v.u;
  unsigned r = (u + 0x7fffu + ((u >> 16) & 1u)) >> 16;
  return (unsigned short)r;
}
__device__ inline float bf2f(unsigned short h) {
  union { unsigned u; float f; } v; v.u = ((unsigned)h) << 16;
  return v.f;
}

// Residual GEMM: act = relu(act@W.T + b) + act, 64x512x512, 8 waves (2mt x 2nt).
// Entry: act ready (barrier done), bq holds bptr slabs [0..PB-2].
// Exit: bq holds nbptr slabs [0..PB-2] (prefetched before the epilogue barrier).
__device__ __forceinline__ void gemm_block(
    const short8* __restrict__ bptr, const short8* __restrict__ nbptr,
    const float* __restrict__ bias,
    short8 (&bq0)[PB], short8 (&bq1)[PB],
    const char* actB, int aBase, int bidx0, int bidx1,
    int wid, int lane, unsigned short (*act)[520])
{
  floatx16 acc00{}, acc01{}, acc10{}, acc11{};
  short8 aq0[PA], aq1[PA];
  #pragma unroll
  for (int i = 0; i < PA - 1; ++i) {
    aq0[i] = *(const short8*)(actB + aBase + i * 32);
    aq1[i] = *(const short8*)(actB + aBase + 33280 + i * 32);
  }
  #pragma unroll
  for (int kt = 0; kt < 32; ++kt) {
    int la = kt + PA - 1;
    if (la < 32) {
      aq0[la % PA] = *(const short8*)(actB + aBase + la * 32);
      aq1[la % PA] = *(const short8*)(actB + aBase + 33280 + la * 32);
    }
    int lb = kt + PB - 1;
    if (lb < 32) {
      bq0[lb % PB] = bptr[lb * 1024 + bidx0];
      bq1[lb % PB] = bptr[lb * 1024 + bidx1];
    }
    acc00 = __builtin_amdgcn_mfma_f32_32x32x16_bf16(aq0[kt % PA], bq0[kt % PB], acc00, 0, 0, 0);
    acc01 = __builtin_amdgcn_mfma_f32_32x32x16_bf16(aq0[kt % PA], bq1[kt % PB], acc01, 0, 0, 0);
    acc10 = __builtin_amdgcn_mfma_f32_32x32x16_bf16(aq1[kt % PA], bq0[kt % PB], acc10, 0, 0, 0);
    acc11 = __builtin_amdgcn_mfma_f32_32x32x16_bf16(aq1[kt % PA], bq1[kt % PB], acc11, 0, 0, 0);
  }
  // prefetch next GEMM's first slabs (in flight across epilogue + later phases)
  #pragma unroll
  for (int i = 0; i < PB - 1; ++i) {
    bq0[i] = nbptr[i * 1024 + bidx0];
    bq1[i] = nbptr[i * 1024 + bidx1];
  }
  __syncthreads();
  int col = lane & 31;
  int ncol0 = (wid * 2 + 0) * 32 + col;
  int ncol1 = (wid * 2 + 1) * 32 + col;
  float bs0 = bias[ncol0], bs1 = bias[ncol1];
  int rb = 4 * (lane >> 5);
  #pragma unroll
  for (int reg = 0; reg < 16; ++reg) {
    int row = (reg & 3) + 8 * (reg >> 2) + rb;
    float v = fmaxf(acc00[reg] + bs0, 0.f) + bf2f(act[row][ncol0]);
    act[row][ncol0] = f2bf(v);
    v = fmaxf(acc01[reg] + bs1, 0.f) + bf2f(act[row][ncol1]);
    act[row][ncol1] = f2bf(v);
    v = fmaxf(acc10[reg] + bs0, 0.f) + bf2f(act[row + 32][ncol0]);
    act[row + 32][ncol0] = f2bf(v);
    v = fmaxf(acc11[reg] + bs1, 0.f) + bf2f(act[row + 32][ncol1]);
    act[row + 32][ncol1] = f2bf(v);
  }
  __syncthreads();
}

// Entire 2-block NODE integration for 64 points per WG (pointwise ODE: no
// inter-WG dependency). 32 dyn evals in one launch; RK4 state lives in LDS.
// NOTE: LDS = 81 KB -> only 1 WG/CU fits regardless, so min-waves-per-EU = 1:
// a tighter bound (R5 used 2) caps VGPRs at 128 and spills the rings -> 3.7 GB
// of scratch traffic per dispatch. 1 gives the 512-VGPR budget, zero spills.
__global__ __launch_bounds__(THREADS, 1) void node_kernel(
    const float* __restrict__ x, float* __restrict__ outp,
    const unsigned short* __restrict__ wfrag,   // [4][512*512] f1w2,f1w3,f2w2,f2w3
    const unsigned short* __restrict__ w1frag,  // [2][8192]  K-padded W1 B-frags
    const unsigned short* __restrict__ w4frag,  // [2][16384] N-padded W4^T B-frags
    const float* __restrict__ sfall,            // [2][4*512]
    const float* __restrict__ b1a, const float* __restrict__ b2a,
    const float* __restrict__ b3a, const float* __restrict__ b4a,
    const float* __restrict__ b1b, const float* __restrict__ b2b,
    const float* __restrict__ b3b, const float* __restrict__ b4b)
{
  __shared__ unsigned short act[64][520];   // pitch 520 u16: conflict-benign b128
  __shared__ float pcur[64][4];
  __shared__ float pev[64][4];
  __shared__ float kst[4][64][4];
  __shared__ float pred[8][64][4];

  const int tid = threadIdx.x;
  const int lane = tid & 63;
  const int wid = tid >> 6;
  const int wg = blockIdx.x;
  const int m0 = wg * 64;
  const int batch = wg >> 6;

  if (tid < 256) {
    int m = tid >> 2, c = tid & 3;
    pcur[m][c] = (c < 3) ? x[m0 * 3 + m * 3 + c] : 0.f;
  }
  __syncthreads();

  const int aBase = (lane & 31) * 1040 + (lane >> 5) * 16;
  const char* actB = (const char*)&act[0][0];
  const int bidx0 = (wid * 2 + 0) * 64 + lane;
  const int bidx1 = (wid * 2 + 1) * 64 + lane;

  const float dt = 0.05f, hdt = 0.025f, dt6 = dt / 6.0f;

  short8 bq0[PB], bq1[PB];
  {  // initial preload: f1 GEMM1 (w2) slabs
    const short8* bp = (const short8*)wfrag;
    #pragma unroll
    for (int i = 0; i < PB - 1; ++i) {
      bq0[i] = bp[i * 1024 + bidx0];
      bq1[i] = bp[i * 1024 + bidx1];
    }
  }

  for (int f = 0; f < 2; ++f) {
    const short8* w2p = (const short8*)(wfrag + (2 * f + 0) * 262144);
    const short8* w3p = (const short8*)(wfrag + (2 * f + 1) * 262144);
    const short8* w1p = (const short8*)(w1frag + f * 8192);
    const short8* w4p = (const short8*)(w4frag + f * 16384);
    const float* sff = sfall + f * 2048 + batch * 512;
    const float* b1 = f ? b1b : b1a;
    const float* b2 = f ? b2b : b2a;
    const float* b3 = f ? b3b : b3a;
    const float* b4 = f ? b4b : b4a;

    for (int step = 0; step < 4; ++step) {
      for (int stage = 0; stage < 4; ++stage) {
        // ---- p_eval ----
        if (tid < 256) {
          int m = tid >> 2, c = tid & 3;
          if (stage == 0) {
            pev[m][c] = pcur[m][c];
          } else {
            float cf = (stage == 3) ? dt : hdt;
            pev[m][c] = fmaf(cf, kst[stage - 1][m][c], pcur[m][c]);
          }
        }
        __syncthreads();

        // ---- phase 1 (MFMA, K=3 zero-padded to 16): act = relu(pe@W1.T+b1)*sf ----
        {
          floatx4 p0 = *(const floatx4*)&pev[lane & 31][0];
          floatx4 p1 = *(const floatx4*)&pev[(lane & 31) + 32][0];
          short8 A0 = (short8){0, 0, 0, 0, 0, 0, 0, 0};
          short8 A1 = A0;
          if ((lane >> 5) == 0) {
            A0[0] = (short)f2bf(p0[0]); A0[1] = (short)f2bf(p0[1]); A0[2] = (short)f2bf(p0[2]);
            A1[0] = (short)f2bf(p1[0]); A1[1] = (short)f2bf(p1[1]); A1[2] = (short)f2bf(p1[2]);
          }
          short8 B0 = w1p[bidx0], B1 = w1p[bidx1];
          floatx16 c00{}, c01{}, c10{}, c11{};
          c00 = __builtin_amdgcn_mfma_f32_32x32x16_bf16(A0, B0, c00, 0, 0, 0);
          c01 = __builtin_amdgcn_mfma_f32_32x32x16_bf16(A0, B1, c01, 0, 0, 0);
          c10 = __builtin_amdgcn_mfma_f32_32x32x16_bf16(A1, B0, c10, 0, 0, 0);
          c11 = __builtin_amdgcn_mfma_f32_32x32x16_bf16(A1, B1, c11, 0, 0, 0);
          int col = lane & 31;
          int ncol0 = (wid * 2 + 0) * 32 + col;
          int ncol1 = (wid * 2 + 1) * 32 + col;
          float bb0 = b1[ncol0], bb1 = b1[ncol1];
          float s0 = sff[ncol0], s1 = sff[ncol1];
          int rb = 4 * (lane >> 5);
          #pragma unroll
          for (int reg = 0; reg < 16; ++reg) {
            int row = (reg & 3) + 8 * (reg >> 2) + rb;
            act[row][ncol0]      = f2bf(fmaxf(c00[reg] + bb0, 0.f) * s0);
            act[row][ncol1]      = f2bf(fmaxf(c01[reg] + bb1, 0.f) * s1);
            act[row + 32][ncol0] = f2bf(fmaxf(c10[reg] + bb0, 0.f) * s0);
            act[row + 32][ncol1] = f2bf(fmaxf(c11[reg] + bb1, 0.f) * s1);
          }
        }
        __syncthreads();

        // ---- GEMM1 (next: w3), GEMM2 (next: following dyn's w2) ----
        gemm_block(w2p, w3p, b2, bq0, bq1, actB, aBase, bidx0, bidx1, wid, lane, act);
        const short8* nxt = (f == 0 && step == 3 && stage == 3)
                                ? (const short8*)(wfrag + 2 * 262144) : w2p;
        gemm_block(w3p, nxt, b3, bq0, bq1, actB, aBase, bidx0, bidx1, wid, lane, act);

        // ---- phase 4 (MFMA, N=3 zero-padded): flow = tanh(act@W4.T + b4) ----
        {
          floatx16 d0{}, d1{};
          #pragma unroll
          for (int kk = 0; kk < 4; ++kk) {
            int kt = wid * 4 + kk;
            short8 a0 = *(const short8*)(actB + aBase + kt * 32);
            short8 a1 = *(const short8*)(actB + aBase + 33280 + kt * 32);
            short8 b = w4p[kt * 64 + lane];
            d0 = __builtin_amdgcn_mfma_f32_32x32x16_bf16(a0, b, d0, 0, 0, 0);
            d1 = __builtin_amdgcn_mfma_f32_32x32x16_bf16(a1, b, d1, 0, 0, 0);
          }
          int col = lane & 31;
          int rb = 4 * (lane >> 5);
          if (col < 3) {
            #pragma unroll
            for (int reg = 0; reg < 16; ++reg) {
              int row = (reg & 3) + 8 * (reg >> 2) + rb;
              pred[wid][row][col] = d0[reg];
              pred[wid][row + 32][col] = d1[reg];
            }
          }
        }
        __syncthreads();
        // reduce 8 wave-partials + bias + tanh -> kst[stage]
        if (tid < 256) {
          int m = tid >> 2, c = tid & 3;
          if (c < 3) {
            float s = b4[c];
            #pragma unroll
            for (int w = 0; w < 8; ++w) s += pred[w][m][c];
            kst[stage][m][c] = tanhf(s);
          } else {
            kst[stage][m][3] = 0.f;
          }
        }
        __syncthreads();
      }
      // ---- RK4 update ----
      if (tid < 256) {
        int m = tid >> 2, c = tid & 3;
        pcur[m][c] += dt6 * (kst[0][m][c] + 2.f * kst[1][m][c] +
                             2.f * kst[2][m][c] + kst[3][m][c]);
      }
      __syncthreads();
    }
  }
  if (tid < 192) outp[m0 * 3 + tid] = pcur[tid / 3][tid % 3];
}

// ---- setup: shuffle W (512x512 fp32 row-major) into fragment-major bf16 ----
__global__ void setup_shuffle(const float* s0, const float* s1, const float* s2,
                              const float* s3, unsigned short* dst) {
  int idx = blockIdx.x * blockDim.x + threadIdx.x;   // 4 * 32768
  int w = idx >> 15;
  int r = idx & 32767;            // (kt*16+nt)*64 + lane
  int lane = r & 63;
  int tile = r >> 6;
  int nt = tile & 15, kt = tile >> 4;
  const float* W = (w == 0) ? s0 : (w == 1) ? s1 : (w == 2) ? s2 : s3;
  int n = nt * 32 + (lane & 31);
  int k0 = kt * 16 + (lane >> 5) * 8;
  const float* src = W + n * 512 + k0;
  unsigned short* d = dst + ((size_t)w << 18) + (size_t)r * 8;
  #pragma unroll
  for (int j = 0; j < 8; ++j) d[j] = f2bf(src[j]);
}

// W1 (512x3) K-padded and W4 (3x512) N-padded fragment buffers
__global__ void setup_small(const float* w1A, const float* w1B,
                            const float* w4A, const float* w4B,
                            unsigned short* w1frag, unsigned short* w4frag) {
  int i = blockIdx.x * blockDim.x + threadIdx.x;   // 49152
  if (i < 16384) {
    int f = i >> 13, r = i & 8191;      // (nt*64+lane)*8 + j
    int j = r & 7, lane = (r >> 3) & 63, nt = r >> 9;
    int n = nt * 32 + (lane & 31), k = (lane >> 5) * 8 + j;
    const float* w1 = f ? w1B : w1A;
    w1frag[f * 8192 + r] = (k < 3) ? f2bf(w1[n * 3 + k]) : (unsigned short)0;
  } else {
    int i2 = i - 16384;
    int f = i2 >> 14, r = i2 & 16383;   // (kt*64+lane)*8 + j
    int j = r & 7, lane = (r >> 3) & 63, kt = r >> 9;
    int n = lane & 31, k = kt * 16 + (lane >> 5) * 8 + j;
    const float* w4 = f ? w4B : w4A;
    w4frag[f * 16384 + r] = (n < 3) ? f2bf(w4[n * 512 + k]) : (unsigned short)0;
  }
}

__global__ void setup_sf(const float* code, const float* cw1, const float* cb1,
                         const float* cw2, const float* cb2, float* sfout) {
  int f = blockIdx.x >> 2, b = blockIdx.x & 3;
  const float* cw = f ? cw2 : cw1;
  const float* cb = f ? cb2 : cb1;
  int j = threadIdx.x;
  const float* c = code + b * 512;
  float s = cb[j];
  for (int k = 0; k < 512; ++k) s = fmaf(c[k], cw[j * 512 + k], s);
  sfout[f * 2048 + b * 512 + j] = tanhf(s);
}

extern "C" void kernel_launch(void* const* d_in, const int* in_sizes, int n_in,
                              void* d_out, int out_size, void* d_ws, size_t ws_size,
                              hipStream_t stream) {
  const float* code = (const float*)d_in[0];
  const float* x    = (const float*)d_in[1];
  char* ws = (char*)d_ws;
  unsigned short* wbf    = (unsigned short*)(ws);                 // 2 MB
  unsigned short* w1frag = (unsigned short*)(ws + 2097152);       // 32 KB
  unsigned short* w4frag = (unsigned short*)(ws + 2097152 + 32768); // 64 KB
  float* sf              = (float*)(ws + 2097152 + 32768 + 65536);  // 16 KB

  setup_shuffle<<<512, 256, 0, stream>>>((const float*)d_in[4], (const float*)d_in[6],
                                         (const float*)d_in[14], (const float*)d_in[16], wbf);
  setup_small<<<192, 256, 0, stream>>>((const float*)d_in[2], (const float*)d_in[12],
                                       (const float*)d_in[8], (const float*)d_in[18],
                                       w1frag, w4frag);
  setup_sf<<<8, 512, 0, stream>>>(code, (const float*)d_in[10], (const float*)d_in[11],
                                  (const float*)d_in[20], (const float*)d_in[21], sf);

  node_kernel<<<256, THREADS, 0, stream>>>(
      x, (float*)d_out, wbf, w1frag, w4frag, sf,
      (const float*)d_in[3],  (const float*)d_in[5],
      (const float*)d_in[7],  (const float*)d_in[9],
      (const float*)d_in[13], (const float*)d_in[15],
      (const float*)d_in[17], (const float*)d_in[19]);
}